// Round 7
// baseline (122.882 us; speedup 1.0000x reference)
//
#include <hip/hip_runtime.h>
#include <math.h>

#define N 8192
#define C 64
#define K 16
#define NB 8
#define HS 72   // bf16 row stride (elements) for LDS tiles: 144B, 16B-aligned, bank-uniform

typedef unsigned long long u64;
typedef unsigned int u32;

typedef float  f32x4v  __attribute__((ext_vector_type(4)));
typedef __bf16 bf16x8  __attribute__((ext_vector_type(8)));

__device__ __forceinline__ unsigned short bfr(float f) {   // f32 -> bf16 RTNE
    u32 u = __float_as_uint(f);
    return (unsigned short)((u + 0x7fffu + ((u >> 16) & 1u)) >> 16);
}

// ---------------- prep: pack pos into float4 ----------------
__global__ __launch_bounds__(256) void prep_pos4(const float* __restrict__ pos,
                                                 float4* __restrict__ pos4) {
    int j = blockIdx.x * 256 + threadIdx.x;
    if (j < N) pos4[j] = make_float4(pos[3*j], pos[3*j+1], pos[3*j+2], 0.0f);
}

// ---------------- Kernel 1: KNN, 4 queries per wave, threshold filter ----------------
// Wave w handles queries i0..i0+3. Pass 1: per-lane min over 128 disjoint candidates per
// query (self NOT excluded; d_self=0). T[q] = 17th-smallest lane-min (>=17 candidates incl.
// self have d<=T => >=16 real). Pass 2: collect {d<=T+margin} via LDS atomic slots. Pass 3:
// exact (f64,idx) rank over collected set, self removed by index. Fallback: serial exact.
__global__ __launch_bounds__(256) void knn_kernel(const float4* __restrict__ pos4,
                                                  int* __restrict__ idx_out) {
    __shared__ int    s_buf[4][4][128];   // collected candidate ids per (wave, query)
    __shared__ double s_d[4][4][128];     // their f64 distances
    __shared__ int    s_cnt[4][4];
    __shared__ double s_fd[4][K];         // fallback top-16 (serial, pathological only)
    __shared__ int    s_fi[4][K];

    const int tid  = threadIdx.x;
    const int w    = tid >> 6;
    const int lane = tid & 63;
    const int i0   = blockIdx.x * 16 + w * 4;

    if (lane < 4) s_cnt[w][lane] = 0;     // wave-private, no barrier needed

    float pix[4], piy[4], piz[4];
    #pragma unroll
    for (int q = 0; q < 4; ++q) {
        const float4 p = pos4[i0 + q];
        pix[q] = p.x; piy[q] = p.y; piz[q] = p.z;
    }

    // ---- pass 1: per-lane min distance per query (self included, d=0) ----
    float mn[4] = {INFINITY, INFINITY, INFINITY, INFINITY};
    #pragma unroll 4
    for (int s = 0; s < 128; ++s) {
        const int j = (s << 6) | lane;
        const float4 pj = pos4[j];
        #pragma unroll
        for (int q = 0; q < 4; ++q) {
            const float dx = pix[q] - pj.x, dy = piy[q] - pj.y, dz = piz[q] - pj.z;
            const float d  = fmaf(dx, dx, fmaf(dy, dy, dz * dz));
            mn[q] = fminf(mn[q], d);
        }
    }

    // ---- T[q] = 17th smallest lane-min (f32 evict-min; tie-pops only make T larger) ----
    float thr[4];
    #pragma unroll
    for (int q = 0; q < 4; ++q) {
        float cur = mn[q], T = 0.0f;
        for (int r = 0; r < K + 1; ++r) {   // 17 rounds: +1 covers self
            float m = cur;
            #pragma unroll
            for (int off = 32; off; off >>= 1) m = fminf(m, __shfl_xor(m, off, 64));
            if (cur == m) cur = INFINITY;
            T = m;
        }
        thr[q] = T + 1e-5f * (sqrtf(T) + T + 1.0f);   // f32-error margin
    }

    // ---- pass 2: collect candidates with d <= thr (self collected too) ----
    #pragma unroll 2
    for (int s = 0; s < 128; ++s) {
        const int j = (s << 6) | lane;
        const float4 pj = pos4[j];
        #pragma unroll
        for (int q = 0; q < 4; ++q) {
            const float dx = pix[q] - pj.x, dy = piy[q] - pj.y, dz = piz[q] - pj.z;
            const float d  = fmaf(dx, dx, fmaf(dy, dy, dz * dz));
            if (d <= thr[q]) {
                const int slot = atomicAdd(&s_cnt[w][q], 1);
                if (slot < 128) s_buf[w][q][slot] = j;
            }
        }
    }

    // ---- pass 3: exact (f64 dist, idx) rank; self removed by index ----
    #pragma unroll
    for (int q = 0; q < 4; ++q) {
        const int iq = i0 + q;
        const int cno = s_cnt[w][q];
        if (cno <= 128) {
            const int cn = cno;
            const double qx = (double)pix[q], qy = (double)piy[q], qz = (double)piz[q];
            for (int sl = lane; sl < cn; sl += 64) {
                const int jj = s_buf[w][q][sl];
                const float4 pj = pos4[jj];
                const double dx = qx - (double)pj.x;
                const double dy = qy - (double)pj.y;
                const double dz = qz - (double)pj.z;
                s_d[w][q][sl] = dx*dx + dy*dy + dz*dz;
            }
            for (int sl = lane; sl < cn; sl += 64) {
                const int    jj = s_buf[w][q][sl];
                if (jj == iq) continue;
                const double dj = s_d[w][q][sl];
                int r = 0;
                for (int e = 0; e < cn; ++e) {
                    const double de = s_d[w][q][e];
                    const int    je = s_buf[w][q][e];
                    r += (de < dj || (de == dj && je < jj)) ? 1 : 0;
                }
                // remove self's contribution (self d=0 is in the set)
                const int selfb = (dj > 0.0 || (dj == 0.0 && iq < jj)) ? 1 : 0;
                const int rr = r - selfb;
                if (rr < K) idx_out[iq*K + rr] = jj;
            }
        } else {
            // pathological safety net: serial exact top-16 over all N
            if (lane == 0) {
                for (int kk = 0; kk < K; ++kk) { s_fd[w][kk] = 1e300; s_fi[w][kk] = 0x7fffffff; }
                const double qx = (double)pix[q], qy = (double)piy[q], qz = (double)piz[q];
                for (int j = 0; j < N; ++j) {
                    if (j == iq) continue;
                    const float4 pj = pos4[j];
                    const double dx = qx - (double)pj.x;
                    const double dy = qy - (double)pj.y;
                    const double dz = qz - (double)pj.z;
                    const double dd = dx*dx + dy*dy + dz*dz;
                    if (dd < s_fd[w][K-1] || (dd == s_fd[w][K-1] && j < s_fi[w][K-1])) {
                        int p = K - 1;
                        while (p > 0 && (dd < s_fd[w][p-1] || (dd == s_fd[w][p-1] && j < s_fi[w][p-1]))) {
                            s_fd[w][p] = s_fd[w][p-1]; s_fi[w][p] = s_fi[w][p-1]; --p;
                        }
                        s_fd[w][p] = dd; s_fi[w][p] = j;
                    }
                }
                for (int kk = 0; kk < K; ++kk) idx_out[iq*K + kk] = s_fi[w][kk];
            }
        }
    }
}

// ---------------- Kernel 2: a_dst/a_src/v projections (unchanged) ----------------
__global__ __launch_bounds__(192) void lin3_kernel(const float* __restrict__ x,
    const float* __restrict__ w_src, const float* __restrict__ w_dst,
    const float* __restrict__ w_lin, const float* __restrict__ b_lin,
    float* __restrict__ a_dst, float* __restrict__ a_src, float* __restrict__ v) {
    __shared__ float xr[C];
    const int i = blockIdx.x;
    const int tid = threadIdx.x;
    if (tid < C) xr[tid] = x[i*C + tid];
    __syncthreads();
    const int cc = tid & 63;
    const int m  = tid >> 6;
    const float* w = (m == 0) ? w_dst : (m == 1) ? w_src : w_lin;
    float acc = (m == 2) ? b_lin[cc] : 0.0f;
    #pragma unroll 8
    for (int k = 0; k < C; ++k) acc += xr[k] * w[k*C + cc];
    float* o = (m == 0) ? a_dst : (m == 1) ? a_src : v;
    o[i*C + cc] = acc;
}

// ---- 16x64 @ 64x64 via 8 MFMA (A: wave-private bf16 tile, B: transposed bf16 weights) ----
__device__ __forceinline__ void mm16x64(const unsigned short* Hb, const unsigned short* wT,
                                        int c0, int sg, f32x4v acc[4]) {
    const bf16x8 a0 = *reinterpret_cast<const bf16x8*>(Hb + c0*HS + sg*8);
    const bf16x8 a1 = *reinterpret_cast<const bf16x8*>(Hb + c0*HS + 32 + sg*8);
    #pragma unroll
    for (int q = 0; q < 4; ++q) {
        const unsigned short* wr = wT + (q*16 + c0)*HS + sg*8;
        const bf16x8 b0 = *reinterpret_cast<const bf16x8*>(wr);
        const bf16x8 b1 = *reinterpret_cast<const bf16x8*>(wr + 32);
        acc[q] = __builtin_amdgcn_mfma_f32_16x16x32_bf16(a0, b0, acc[q], 0, 0, 0);
        acc[q] = __builtin_amdgcn_mfma_f32_16x16x32_bf16(a1, b1, acc[q], 0, 0, 0);
    }
}

// ---------------- Kernel 3: edge pipeline, wave-per-node, MFMA matmuls (unchanged) ----------
__global__ __launch_bounds__(512, 4) void edge_kernel(
    const float* __restrict__ x, const float* __restrict__ pos,
    const int* __restrict__ nidx,
    const float* __restrict__ a_dst, const float* __restrict__ a_src, const float* __restrict__ v,
    const float* __restrict__ p1w, const float* __restrict__ p1b,
    const float* __restrict__ p1g, const float* __restrict__ p1bt,
    const float* __restrict__ p2w, const float* __restrict__ p2b,
    const float* __restrict__ a1w, const float* __restrict__ a1b,
    const float* __restrict__ a1g, const float* __restrict__ a1bt,
    const float* __restrict__ a2w, const float* __restrict__ a2b,
    const float* __restrict__ uw, const float* __restrict__ ub,
    float* __restrict__ out) {

    __shared__ __align__(16) unsigned short sWT[3 * C * HS];
    __shared__ __align__(16) float          uwf[C * C];
    __shared__ __align__(16) unsigned short sHb[NB * K * HS];
    __shared__ __align__(16) float4         sMisc4[NB * 16];
    __shared__ int                          sIdx[NB * K];

    const int tid  = threadIdx.x;
    const int w    = tid >> 6;
    const int lane = tid & 63;
    const int c0   = tid & 15;
    const int sg   = (tid >> 4) & 3;
    const int n    = blockIdx.x * NB + w;

    unsigned short* Hlb = sHb + w * (K * HS);
    float4*         Ml4 = sMisc4 + w * 16;
    float*          Mlf = (float*)Ml4;
    int*            Il  = sIdx + w * K;

    {
        const float* mats[3] = {p2w, a1w, a2w};
        #pragma unroll
        for (int m = 0; m < 3; ++m) {
            const float4* s4 = (const float4*)mats[m];
            unsigned short* dst = sWT + m * (C * HS);
            const float4 v0 = s4[tid*2], v1 = s4[tid*2 + 1];
            const int base = tid * 8;
            const int e = base >> 6, cc = base & 63;
            dst[(cc+0)*HS + e] = bfr(v0.x); dst[(cc+1)*HS + e] = bfr(v0.y);
            dst[(cc+2)*HS + e] = bfr(v0.z); dst[(cc+3)*HS + e] = bfr(v0.w);
            dst[(cc+4)*HS + e] = bfr(v1.x); dst[(cc+5)*HS + e] = bfr(v1.y);
            dst[(cc+6)*HS + e] = bfr(v1.z); dst[(cc+7)*HS + e] = bfr(v1.w);
        }
        float4* du = (float4*)uwf;
        const float4* su = (const float4*)uw;
        du[tid] = su[tid]; du[tid + 512] = su[tid + 512];
    }
    if (lane < K) {
        const int j = nidx[n*K + lane];
        Il[lane] = j;
        float4 r;
        r.x = pos[3*n]   - pos[3*j];
        r.y = pos[3*n+1] - pos[3*j+1];
        r.z = pos[3*n+2] - pos[3*j+2];
        r.w = 0.0f;
        Ml4[lane] = r;
    }
    __syncthreads();

    int c4[4];
    #pragma unroll
    for (int q = 0; q < 4; ++q) c4[q] = q*16 + c0;

    {
        float W0[4], W1[4], W2[4], B_[4], G_[4], BT[4];
        #pragma unroll
        for (int q = 0; q < 4; ++q) {
            const int cc = c4[q];
            W0[q] = p1w[cc]; W1[q] = p1w[C + cc]; W2[q] = p1w[2*C + cc];
            B_[q] = p1b[cc]; G_[q] = p1g[cc];     BT[q] = p1bt[cc];
        }
        #pragma unroll
        for (int r = 0; r < 4; ++r) {
            const float4 rr = Ml4[sg*4 + r];
            #pragma unroll
            for (int q = 0; q < 4; ++q) {
                float t = fmaf(rr.x, W0[q], fmaf(rr.y, W1[q], fmaf(rr.z, W2[q], B_[q])));
                t = fmaxf(fmaf(G_[q], t, BT[q]), 0.0f);
                Hlb[(sg*4 + r)*HS + c4[q]] = bfr(t);
            }
        }
    }

    f32x4v acc[4], del[4];
    #pragma unroll
    for (int q = 0; q < 4; ++q) { const float b_ = p2b[c4[q]]; acc[q] = (f32x4v){b_, b_, b_, b_}; }
    mm16x64(Hlb, sWT, c0, sg, acc);
    #pragma unroll
    for (int q = 0; q < 4; ++q) del[q] = acc[q];

    int jr[4];
    #pragma unroll
    for (int r = 0; r < 4; ++r) jr[r] = Il[sg*4 + r];
    float adstv[4];
    #pragma unroll
    for (int q = 0; q < 4; ++q) adstv[q] = a_dst[n*C + c4[q]];

    #pragma unroll
    for (int r = 0; r < 4; ++r) {
        #pragma unroll
        for (int q = 0; q < 4; ++q) {
            const float t = adstv[q] - a_src[jr[r]*C + c4[q]] + acc[q][r];
            Hlb[(sg*4 + r)*HS + c4[q]] = bfr(t);
        }
    }

    #pragma unroll
    for (int q = 0; q < 4; ++q) { const float b_ = a1b[c4[q]]; acc[q] = (f32x4v){b_, b_, b_, b_}; }
    mm16x64(Hlb, sWT + C*HS, c0, sg, acc);
    #pragma unroll
    for (int q = 0; q < 4; ++q) {
        const float g_ = a1g[c4[q]], bt_ = a1bt[c4[q]];
        #pragma unroll
        for (int r = 0; r < 4; ++r) {
            const float h2 = fmaxf(fmaf(g_, acc[q][r], bt_), 0.0f);
            Hlb[(sg*4 + r)*HS + c4[q]] = bfr(h2);
        }
    }

    #pragma unroll
    for (int q = 0; q < 4; ++q) { const float b_ = a2b[c4[q]]; acc[q] = (f32x4v){b_, b_, b_, b_}; }
    mm16x64(Hlb, sWT + 2*C*HS, c0, sg, acc);

    float o_[4];
    #pragma unroll
    for (int q = 0; q < 4; ++q) {
        float vgq[4];
        #pragma unroll
        for (int r = 0; r < 4; ++r) vgq[r] = v[jr[r]*C + c4[q]];
        float lm = fmaxf(fmaxf(acc[q][0], acc[q][1]), fmaxf(acc[q][2], acc[q][3]));
        lm = fmaxf(lm, __shfl_xor(lm, 16, 64));
        lm = fmaxf(lm, __shfl_xor(lm, 32, 64));
        float ls = 0.0f, lo = 0.0f;
        #pragma unroll
        for (int r = 0; r < 4; ++r) {
            const float e_ = __expf(acc[q][r] - lm);
            ls += e_;
            lo = fmaf(e_, vgq[r] + del[q][r], lo);
        }
        ls += __shfl_xor(ls, 16, 64); ls += __shfl_xor(ls, 32, 64);
        lo += __shfl_xor(lo, 16, 64); lo += __shfl_xor(lo, 32, 64);
        o_[q] = lo / ls;
    }
    if (sg == 0) {
        #pragma unroll
        for (int q = 0; q < 4; ++q) Mlf[c4[q]] = o_[q];
    }

    float facc = ub[lane] + x[n*C + lane];
    #pragma unroll 4
    for (int e4 = 0; e4 < 16; ++e4) {
        const float4 g4 = Ml4[e4];
        facc = fmaf(g4.x, uwf[(e4*4+0)*C + lane], facc);
        facc = fmaf(g4.y, uwf[(e4*4+1)*C + lane], facc);
        facc = fmaf(g4.z, uwf[(e4*4+2)*C + lane], facc);
        facc = fmaf(g4.w, uwf[(e4*4+3)*C + lane], facc);
    }
    out[n*C + lane] = facc;
}

extern "C" void kernel_launch(void* const* d_in, const int* in_sizes, int n_in,
                              void* d_out, int out_size, void* d_ws, size_t ws_size,
                              hipStream_t stream) {
    const float* x     = (const float*)d_in[0];
    const float* pos   = (const float*)d_in[1];
    const float* w_src = (const float*)d_in[2];
    const float* w_dst = (const float*)d_in[3];
    const float* w_lin = (const float*)d_in[4];
    const float* b_lin = (const float*)d_in[5];
    const float* p1w   = (const float*)d_in[6];
    const float* p1b   = (const float*)d_in[7];
    const float* p1g   = (const float*)d_in[8];
    const float* p1bt  = (const float*)d_in[9];
    const float* p2w   = (const float*)d_in[10];
    const float* p2b   = (const float*)d_in[11];
    const float* a1w   = (const float*)d_in[12];
    const float* a1b   = (const float*)d_in[13];
    const float* a1g   = (const float*)d_in[14];
    const float* a1bt  = (const float*)d_in[15];
    const float* a2w   = (const float*)d_in[16];
    const float* a2b   = (const float*)d_in[17];
    const float* uw    = (const float*)d_in[18];
    const float* ub    = (const float*)d_in[19];
    float* out = (float*)d_out;

    char* ws    = (char*)d_ws;
    int*    idx  = (int*)ws;                                    // N*K ints
    float*  adst = (float*)(ws + (size_t)N*K*sizeof(int));
    float*  asrc = adst + (size_t)N*C;
    float*  vv   = asrc + (size_t)N*C;
    float4* pos4 = (float4*)(vv + (size_t)N*C);                 // N float4

    prep_pos4 <<<(N + 255)/256, 256, 0, stream>>>(pos, pos4);
    knn_kernel<<<N/16, 256, 0, stream>>>(pos4, idx);
    lin3_kernel<<<N, 192, 0, stream>>>(x, w_src, w_dst, w_lin, b_lin, adst, asrc, vv);
    edge_kernel<<<N/NB, 512, 0, stream>>>(x, pos, idx, adst, asrc, vv,
        p1w, p1b, p1g, p1bt, p2w, p2b, a1w, a1b, a1g, a1bt, a2w, a2b, uw, ub, out);
}

// Round 8
// 84.538 us; speedup vs baseline: 1.4536x; 1.4536x over previous
//
#include <hip/hip_runtime.h>
#include <math.h>

#define N 8192
#define C 64
#define K 16
#define NB 8
#define HS 72   // bf16 row stride (elements) for LDS tiles: 144B, 16B-aligned, bank-uniform

typedef unsigned long long u64;
typedef unsigned int u32;

typedef float  f32x4v  __attribute__((ext_vector_type(4)));
typedef __bf16 bf16x8  __attribute__((ext_vector_type(8)));

__device__ __forceinline__ unsigned short bfr(float f) {   // f32 -> bf16 RTNE
    u32 u = __float_as_uint(f);
    return (unsigned short)((u + 0x7fffu + ((u >> 16) & 1u)) >> 16);
}

// ---------------- prep: pack pos into float4 ----------------
__global__ __launch_bounds__(256) void prep_pos4(const float* __restrict__ pos,
                                                 float4* __restrict__ pos4) {
    int j = blockIdx.x * 256 + threadIdx.x;
    if (j < N) pos4[j] = make_float4(pos[3*j], pos[3*j+1], pos[3*j+2], 0.0f);
}

// ---------------- Kernel 1: KNN, block-per-4-queries, split stream ----------------
// Block (4 waves, 256 thr) handles queries i0..i0+3; thread t streams candidates
// j = s*256 + t (32 each, coalesced), computing distances to all 4 queries (4x load
// amortization). T[q] = 17th-smallest of the 256 per-thread minima (disjoint subsets,
// self counted once) + f32-error margin. Collect {d<=thr} via LDS atomics; exact
// (f64,idx) rank over collected set, self removed by index. Serial-exact fallback.
__global__ __launch_bounds__(256) void knn_kernel(const float4* __restrict__ pos4,
                                                  int* __restrict__ idx_out) {
    __shared__ float  smin[4][256];   // [query][thread] pass-1 minima (4 KB)
    __shared__ float  sthr[4];
    __shared__ int    s_buf[4][128];  // collected ids per query (2 KB)
    __shared__ double s_d[4][128];    // f64 distances (4 KB)
    __shared__ int    s_cnt[4];
    __shared__ double s_fd[4][K];     // fallback (pathological only)
    __shared__ int    s_fi[4][K];

    const int tid  = threadIdx.x;
    const int w    = tid >> 6;
    const int lane = tid & 63;
    const int i0   = blockIdx.x * 4;

    if (tid < 4) s_cnt[tid] = 0;

    float pix[4], piy[4], piz[4];
    #pragma unroll
    for (int q = 0; q < 4; ++q) {
        const float4 p = pos4[i0 + q];
        pix[q] = p.x; piy[q] = p.y; piz[q] = p.z;
    }

    // ---- pass 1: per-thread min per query over 32 disjoint candidates (self incl., d=0) ----
    float mn[4] = {INFINITY, INFINITY, INFINITY, INFINITY};
    #pragma unroll 4
    for (int s = 0; s < 32; ++s) {
        const int j = (s << 8) + tid;
        const float4 pj = pos4[j];
        #pragma unroll
        for (int q = 0; q < 4; ++q) {
            const float dx = pix[q] - pj.x, dy = piy[q] - pj.y, dz = piz[q] - pj.z;
            const float d  = fmaf(dx, dx, fmaf(dy, dy, dz * dz));
            mn[q] = fminf(mn[q], d);
        }
    }
    #pragma unroll
    for (int q = 0; q < 4; ++q) smin[q][tid] = mn[q];
    __syncthreads();

    // ---- wave w: T = 17th-smallest of query w's 256 thread-minima (evict-min; dup-pops
    //      only enlarge T = conservative) ----
    {
        float v0 = smin[w][lane];
        float v1 = smin[w][lane + 64];
        float v2 = smin[w][lane + 128];
        float v3 = smin[w][lane + 192];
        float T = 0.0f;
        for (int r = 0; r < K + 1; ++r) {   // 17 rounds (+1 covers self)
            float lm = fminf(fminf(v0, v1), fminf(v2, v3));
            float m = lm;
            #pragma unroll
            for (int off = 32; off; off >>= 1) m = fminf(m, __shfl_xor(m, off, 64));
            T = m;
            v0 = (v0 == m) ? INFINITY : v0;
            v1 = (v1 == m) ? INFINITY : v1;
            v2 = (v2 == m) ? INFINITY : v2;
            v3 = (v3 == m) ? INFINITY : v3;
        }
        if (lane == 0) sthr[w] = T + 1e-5f * (sqrtf(T) + T + 1.0f);   // f32-error margin
    }
    __syncthreads();

    float thr[4];
    #pragma unroll
    for (int q = 0; q < 4; ++q) thr[q] = sthr[q];

    // ---- pass 2: re-stream, collect {d <= thr[q]} (self collected too) ----
    #pragma unroll 2
    for (int s = 0; s < 32; ++s) {
        const int j = (s << 8) + tid;
        const float4 pj = pos4[j];
        #pragma unroll
        for (int q = 0; q < 4; ++q) {
            const float dx = pix[q] - pj.x, dy = piy[q] - pj.y, dz = piz[q] - pj.z;
            const float d  = fmaf(dx, dx, fmaf(dy, dy, dz * dz));
            if (d <= thr[q]) {
                const int slot = atomicAdd(&s_cnt[q], 1);
                if (slot < 128) s_buf[q][slot] = j;
            }
        }
    }
    __syncthreads();

    // ---- pass 3: wave w does exact (f64 dist, idx) rank for query w; self removed ----
    {
        const int q  = w;
        const int iq = i0 + q;
        const int cno = s_cnt[q];
        if (cno <= 128) {
            const int cn = cno;
            const double qx = (double)pix[q], qy = (double)piy[q], qz = (double)piz[q];
            for (int sl = lane; sl < cn; sl += 64) {
                const int jj = s_buf[q][sl];
                const float4 pj = pos4[jj];
                const double dx = qx - (double)pj.x;
                const double dy = qy - (double)pj.y;
                const double dz = qz - (double)pj.z;
                s_d[q][sl] = dx*dx + dy*dy + dz*dz;
            }
            for (int sl = lane; sl < cn; sl += 64) {
                const int jj = s_buf[q][sl];
                if (jj == iq) continue;
                const double dj = s_d[q][sl];
                int r = 0;
                for (int e = 0; e < cn; ++e) {
                    const double de = s_d[q][e];
                    const int    je = s_buf[q][e];
                    r += (de < dj || (de == dj && je < jj)) ? 1 : 0;
                }
                const int selfb = (dj > 0.0 || (dj == 0.0 && iq < jj)) ? 1 : 0;
                const int rr = r - selfb;
                if (rr < K) idx_out[iq*K + rr] = jj;
            }
        } else {
            if (lane == 0) {
                for (int kk = 0; kk < K; ++kk) { s_fd[w][kk] = 1e300; s_fi[w][kk] = 0x7fffffff; }
                const double qx = (double)pix[q], qy = (double)piy[q], qz = (double)piz[q];
                for (int j = 0; j < N; ++j) {
                    if (j == iq) continue;
                    const float4 pj = pos4[j];
                    const double dx = qx - (double)pj.x;
                    const double dy = qy - (double)pj.y;
                    const double dz = qz - (double)pj.z;
                    const double dd = dx*dx + dy*dy + dz*dz;
                    if (dd < s_fd[w][K-1] || (dd == s_fd[w][K-1] && j < s_fi[w][K-1])) {
                        int p = K - 1;
                        while (p > 0 && (dd < s_fd[w][p-1] || (dd == s_fd[w][p-1] && j < s_fi[w][p-1]))) {
                            s_fd[w][p] = s_fd[w][p-1]; s_fi[w][p] = s_fi[w][p-1]; --p;
                        }
                        s_fd[w][p] = dd; s_fi[w][p] = j;
                    }
                }
                for (int kk = 0; kk < K; ++kk) idx_out[iq*K + kk] = s_fi[w][kk];
            }
        }
    }
}

// ---------------- Kernel 2: a_dst/a_src/v projections (unchanged) ----------------
__global__ __launch_bounds__(192) void lin3_kernel(const float* __restrict__ x,
    const float* __restrict__ w_src, const float* __restrict__ w_dst,
    const float* __restrict__ w_lin, const float* __restrict__ b_lin,
    float* __restrict__ a_dst, float* __restrict__ a_src, float* __restrict__ v) {
    __shared__ float xr[C];
    const int i = blockIdx.x;
    const int tid = threadIdx.x;
    if (tid < C) xr[tid] = x[i*C + tid];
    __syncthreads();
    const int cc = tid & 63;
    const int m  = tid >> 6;
    const float* w = (m == 0) ? w_dst : (m == 1) ? w_src : w_lin;
    float acc = (m == 2) ? b_lin[cc] : 0.0f;
    #pragma unroll 8
    for (int k = 0; k < C; ++k) acc += xr[k] * w[k*C + cc];
    float* o = (m == 0) ? a_dst : (m == 1) ? a_src : v;
    o[i*C + cc] = acc;
}

// ---- 16x64 @ 64x64 via 8 MFMA (A: wave-private bf16 tile, B: transposed bf16 weights) ----
__device__ __forceinline__ void mm16x64(const unsigned short* Hb, const unsigned short* wT,
                                        int c0, int sg, f32x4v acc[4]) {
    const bf16x8 a0 = *reinterpret_cast<const bf16x8*>(Hb + c0*HS + sg*8);
    const bf16x8 a1 = *reinterpret_cast<const bf16x8*>(Hb + c0*HS + 32 + sg*8);
    #pragma unroll
    for (int q = 0; q < 4; ++q) {
        const unsigned short* wr = wT + (q*16 + c0)*HS + sg*8;
        const bf16x8 b0 = *reinterpret_cast<const bf16x8*>(wr);
        const bf16x8 b1 = *reinterpret_cast<const bf16x8*>(wr + 32);
        acc[q] = __builtin_amdgcn_mfma_f32_16x16x32_bf16(a0, b0, acc[q], 0, 0, 0);
        acc[q] = __builtin_amdgcn_mfma_f32_16x16x32_bf16(a1, b1, acc[q], 0, 0, 0);
    }
}

// ---------------- Kernel 3: edge pipeline, wave-per-node, MFMA matmuls (unchanged) ----------
__global__ __launch_bounds__(512, 4) void edge_kernel(
    const float* __restrict__ x, const float* __restrict__ pos,
    const int* __restrict__ nidx,
    const float* __restrict__ a_dst, const float* __restrict__ a_src, const float* __restrict__ v,
    const float* __restrict__ p1w, const float* __restrict__ p1b,
    const float* __restrict__ p1g, const float* __restrict__ p1bt,
    const float* __restrict__ p2w, const float* __restrict__ p2b,
    const float* __restrict__ a1w, const float* __restrict__ a1b,
    const float* __restrict__ a1g, const float* __restrict__ a1bt,
    const float* __restrict__ a2w, const float* __restrict__ a2b,
    const float* __restrict__ uw, const float* __restrict__ ub,
    float* __restrict__ out) {

    __shared__ __align__(16) unsigned short sWT[3 * C * HS];
    __shared__ __align__(16) float          uwf[C * C];
    __shared__ __align__(16) unsigned short sHb[NB * K * HS];
    __shared__ __align__(16) float4         sMisc4[NB * 16];
    __shared__ int                          sIdx[NB * K];

    const int tid  = threadIdx.x;
    const int w    = tid >> 6;
    const int lane = tid & 63;
    const int c0   = tid & 15;
    const int sg   = (tid >> 4) & 3;
    const int n    = blockIdx.x * NB + w;

    unsigned short* Hlb = sHb + w * (K * HS);
    float4*         Ml4 = sMisc4 + w * 16;
    float*          Mlf = (float*)Ml4;
    int*            Il  = sIdx + w * K;

    {
        const float* mats[3] = {p2w, a1w, a2w};
        #pragma unroll
        for (int m = 0; m < 3; ++m) {
            const float4* s4 = (const float4*)mats[m];
            unsigned short* dst = sWT + m * (C * HS);
            const float4 v0 = s4[tid*2], v1 = s4[tid*2 + 1];
            const int base = tid * 8;
            const int e = base >> 6, cc = base & 63;
            dst[(cc+0)*HS + e] = bfr(v0.x); dst[(cc+1)*HS + e] = bfr(v0.y);
            dst[(cc+2)*HS + e] = bfr(v0.z); dst[(cc+3)*HS + e] = bfr(v0.w);
            dst[(cc+4)*HS + e] = bfr(v1.x); dst[(cc+5)*HS + e] = bfr(v1.y);
            dst[(cc+6)*HS + e] = bfr(v1.z); dst[(cc+7)*HS + e] = bfr(v1.w);
        }
        float4* du = (float4*)uwf;
        const float4* su = (const float4*)uw;
        du[tid] = su[tid]; du[tid + 512] = su[tid + 512];
    }
    if (lane < K) {
        const int j = nidx[n*K + lane];
        Il[lane] = j;
        float4 r;
        r.x = pos[3*n]   - pos[3*j];
        r.y = pos[3*n+1] - pos[3*j+1];
        r.z = pos[3*n+2] - pos[3*j+2];
        r.w = 0.0f;
        Ml4[lane] = r;
    }
    __syncthreads();

    int c4[4];
    #pragma unroll
    for (int q = 0; q < 4; ++q) c4[q] = q*16 + c0;

    {
        float W0[4], W1[4], W2[4], B_[4], G_[4], BT[4];
        #pragma unroll
        for (int q = 0; q < 4; ++q) {
            const int cc = c4[q];
            W0[q] = p1w[cc]; W1[q] = p1w[C + cc]; W2[q] = p1w[2*C + cc];
            B_[q] = p1b[cc]; G_[q] = p1g[cc];     BT[q] = p1bt[cc];
        }
        #pragma unroll
        for (int r = 0; r < 4; ++r) {
            const float4 rr = Ml4[sg*4 + r];
            #pragma unroll
            for (int q = 0; q < 4; ++q) {
                float t = fmaf(rr.x, W0[q], fmaf(rr.y, W1[q], fmaf(rr.z, W2[q], B_[q])));
                t = fmaxf(fmaf(G_[q], t, BT[q]), 0.0f);
                Hlb[(sg*4 + r)*HS + c4[q]] = bfr(t);
            }
        }
    }

    f32x4v acc[4], del[4];
    #pragma unroll
    for (int q = 0; q < 4; ++q) { const float b_ = p2b[c4[q]]; acc[q] = (f32x4v){b_, b_, b_, b_}; }
    mm16x64(Hlb, sWT, c0, sg, acc);
    #pragma unroll
    for (int q = 0; q < 4; ++q) del[q] = acc[q];

    int jr[4];
    #pragma unroll
    for (int r = 0; r < 4; ++r) jr[r] = Il[sg*4 + r];
    float adstv[4];
    #pragma unroll
    for (int q = 0; q < 4; ++q) adstv[q] = a_dst[n*C + c4[q]];

    #pragma unroll
    for (int r = 0; r < 4; ++r) {
        #pragma unroll
        for (int q = 0; q < 4; ++q) {
            const float t = adstv[q] - a_src[jr[r]*C + c4[q]] + acc[q][r];
            Hlb[(sg*4 + r)*HS + c4[q]] = bfr(t);
        }
    }

    #pragma unroll
    for (int q = 0; q < 4; ++q) { const float b_ = a1b[c4[q]]; acc[q] = (f32x4v){b_, b_, b_, b_}; }
    mm16x64(Hlb, sWT + C*HS, c0, sg, acc);
    #pragma unroll
    for (int q = 0; q < 4; ++q) {
        const float g_ = a1g[c4[q]], bt_ = a1bt[c4[q]];
        #pragma unroll
        for (int r = 0; r < 4; ++r) {
            const float h2 = fmaxf(fmaf(g_, acc[q][r], bt_), 0.0f);
            Hlb[(sg*4 + r)*HS + c4[q]] = bfr(h2);
        }
    }

    #pragma unroll
    for (int q = 0; q < 4; ++q) { const float b_ = a2b[c4[q]]; acc[q] = (f32x4v){b_, b_, b_, b_}; }
    mm16x64(Hlb, sWT + 2*C*HS, c0, sg, acc);

    float o_[4];
    #pragma unroll
    for (int q = 0; q < 4; ++q) {
        float vgq[4];
        #pragma unroll
        for (int r = 0; r < 4; ++r) vgq[r] = v[jr[r]*C + c4[q]];
        float lm = fmaxf(fmaxf(acc[q][0], acc[q][1]), fmaxf(acc[q][2], acc[q][3]));
        lm = fmaxf(lm, __shfl_xor(lm, 16, 64));
        lm = fmaxf(lm, __shfl_xor(lm, 32, 64));
        float ls = 0.0f, lo = 0.0f;
        #pragma unroll
        for (int r = 0; r < 4; ++r) {
            const float e_ = __expf(acc[q][r] - lm);
            ls += e_;
            lo = fmaf(e_, vgq[r] + del[q][r], lo);
        }
        ls += __shfl_xor(ls, 16, 64); ls += __shfl_xor(ls, 32, 64);
        lo += __shfl_xor(lo, 16, 64); lo += __shfl_xor(lo, 32, 64);
        o_[q] = lo / ls;
    }
    if (sg == 0) {
        #pragma unroll
        for (int q = 0; q < 4; ++q) Mlf[c4[q]] = o_[q];
    }

    float facc = ub[lane] + x[n*C + lane];
    #pragma unroll 4
    for (int e4 = 0; e4 < 16; ++e4) {
        const float4 g4 = Ml4[e4];
        facc = fmaf(g4.x, uwf[(e4*4+0)*C + lane], facc);
        facc = fmaf(g4.y, uwf[(e4*4+1)*C + lane], facc);
        facc = fmaf(g4.z, uwf[(e4*4+2)*C + lane], facc);
        facc = fmaf(g4.w, uwf[(e4*4+3)*C + lane], facc);
    }
    out[n*C + lane] = facc;
}

extern "C" void kernel_launch(void* const* d_in, const int* in_sizes, int n_in,
                              void* d_out, int out_size, void* d_ws, size_t ws_size,
                              hipStream_t stream) {
    const float* x     = (const float*)d_in[0];
    const float* pos   = (const float*)d_in[1];
    const float* w_src = (const float*)d_in[2];
    const float* w_dst = (const float*)d_in[3];
    const float* w_lin = (const float*)d_in[4];
    const float* b_lin = (const float*)d_in[5];
    const float* p1w   = (const float*)d_in[6];
    const float* p1b   = (const float*)d_in[7];
    const float* p1g   = (const float*)d_in[8];
    const float* p1bt  = (const float*)d_in[9];
    const float* p2w   = (const float*)d_in[10];
    const float* p2b   = (const float*)d_in[11];
    const float* a1w   = (const float*)d_in[12];
    const float* a1b   = (const float*)d_in[13];
    const float* a1g   = (const float*)d_in[14];
    const float* a1bt  = (const float*)d_in[15];
    const float* a2w   = (const float*)d_in[16];
    const float* a2b   = (const float*)d_in[17];
    const float* uw    = (const float*)d_in[18];
    const float* ub    = (const float*)d_in[19];
    float* out = (float*)d_out;

    char* ws    = (char*)d_ws;
    int*    idx  = (int*)ws;                                    // N*K ints
    float*  adst = (float*)(ws + (size_t)N*K*sizeof(int));
    float*  asrc = adst + (size_t)N*C;
    float*  vv   = asrc + (size_t)N*C;
    float4* pos4 = (float4*)(vv + (size_t)N*C);                 // N float4

    prep_pos4 <<<(N + 255)/256, 256, 0, stream>>>(pos, pos4);
    knn_kernel<<<N/4, 256, 0, stream>>>(pos4, idx);
    lin3_kernel<<<N, 192, 0, stream>>>(x, w_src, w_dst, w_lin, b_lin, adst, asrc, vv);
    edge_kernel<<<N/NB, 512, 0, stream>>>(x, pos, idx, adst, asrc, vv,
        p1w, p1b, p1g, p1bt, p2w, p2b, a1w, a1b, a1g, a1bt, a2w, a2b, uw, ub, out);
}

// Round 9
// 80.797 us; speedup vs baseline: 1.5209x; 1.0463x over previous
//
#include <hip/hip_runtime.h>
#include <math.h>

#define N 8192
#define C 64
#define K 16
#define NB 8
#define QB 8
#define LNODES 8
#define HS 72   // bf16 row stride (elements) for LDS tiles: 144B, 16B-aligned, bank-uniform

typedef unsigned long long u64;
typedef unsigned int u32;

typedef float  f32x4v  __attribute__((ext_vector_type(4)));
typedef __bf16 bf16x8  __attribute__((ext_vector_type(8)));

__device__ __forceinline__ unsigned short bfr(float f) {   // f32 -> bf16 RTNE
    u32 u = __float_as_uint(f);
    return (unsigned short)((u + 0x7fffu + ((u >> 16) & 1u)) >> 16);
}

// ---------------- prep: pack pos into float4, w = |p|^2 ----------------
__global__ __launch_bounds__(256) void prep_pos4(const float* __restrict__ pos,
                                                 float4* __restrict__ pos4) {
    int j = blockIdx.x * 256 + threadIdx.x;
    if (j < N) {
        const float px = pos[3*j], py = pos[3*j+1], pz = pos[3*j+2];
        pos4[j] = make_float4(px, py, pz, fmaf(px, px, fmaf(py, py, pz * pz)));
    }
}

// ---------------- prep: bf16-transposed edge weights wT[m][c][e] ----------------
__global__ __launch_bounds__(256) void prep_wT(const float* __restrict__ p2w,
                                               const float* __restrict__ a1w,
                                               const float* __restrict__ a2w,
                                               unsigned short* __restrict__ wT) {
    int t = blockIdx.x * 256 + threadIdx.x;
    if (t < 3 * C * C) {
        const int m = t >> 12, r = t & (C*C - 1);
        const int e = r >> 6, c = r & 63;
        const float* w = (m == 0) ? p2w : (m == 1) ? a1w : a2w;
        wT[m * C * HS + c * HS + e] = bfr(w[r]);
    }
}

// ---------------- Kernel 1: KNN, block-per-8-queries, ordering-proxy distances -------------
// Block (8 waves, 512 thr) handles queries i0..i0+7; thread t streams candidates
// j = s*512 + t (16 each, coalesced). Ordering proxy pr(j) = |pj|^2 - 2*dot(q,pj)
// (= d^2 - |q|^2, monotone in d^2). T[q] = 17th-smallest of 512 disjoint-subset
// per-thread minima (self counted once) + f32-error margin. Collect {pr<=thr} via LDS
// atomics; exact (f64,idx) rank over collected set, self removed by index. Fallback serial.
__global__ __launch_bounds__(512) void knn_kernel(const float4* __restrict__ pos4,
                                                  int* __restrict__ idx_out) {
    __shared__ float  smin[QB][512];   // 16 KB
    __shared__ float  sthr[QB];
    __shared__ int    s_buf[QB][96];   // 3 KB
    __shared__ double s_d[QB][96];     // 6 KB
    __shared__ int    s_cnt[QB];
    __shared__ double s_fd[QB][K];     // fallback (pathological only)
    __shared__ int    s_fi[QB][K];

    const int tid  = threadIdx.x;
    const int w    = tid >> 6;
    const int lane = tid & 63;
    const int i0   = blockIdx.x * QB;

    if (tid < QB) s_cnt[tid] = 0;

    float qx[QB], qy[QB], qz[QB];
    #pragma unroll
    for (int q = 0; q < QB; ++q) {
        const float4 p = pos4[i0 + q];
        qx[q] = p.x; qy[q] = p.y; qz[q] = p.z;
    }

    // ---- pass 1: per-thread proxy-min per query over 16 disjoint candidates ----
    float mn[QB];
    #pragma unroll
    for (int q = 0; q < QB; ++q) mn[q] = INFINITY;
    #pragma unroll 4
    for (int s = 0; s < 16; ++s) {
        const int j = (s << 9) + tid;
        const float4 pj = pos4[j];
        #pragma unroll
        for (int q = 0; q < QB; ++q) {
            const float dot = fmaf(qx[q], pj.x, fmaf(qy[q], pj.y, qz[q] * pj.z));
            const float pr  = fmaf(-2.0f, dot, pj.w);
            mn[q] = fminf(mn[q], pr);
        }
    }
    #pragma unroll
    for (int q = 0; q < QB; ++q) smin[q][tid] = mn[q];
    __syncthreads();

    // ---- wave w: T = 17th-smallest of query w's 512 thread-minima (evict-min;
    //      duplicate-pops only enlarge T = conservative) ----
    {
        float v[8];
        #pragma unroll
        for (int k = 0; k < 8; ++k) v[k] = smin[w][lane + 64*k];
        float T = 0.0f;
        for (int r = 0; r < K + 1; ++r) {   // 17 rounds (+1 covers self)
            float m = fminf(fminf(fminf(v[0], v[1]), fminf(v[2], v[3])),
                            fminf(fminf(v[4], v[5]), fminf(v[6], v[7])));
            #pragma unroll
            for (int off = 32; off; off >>= 1) m = fminf(m, __shfl_xor(m, off, 64));
            T = m;
            #pragma unroll
            for (int k = 0; k < 8; ++k) v[k] = (v[k] == m) ? INFINITY : v[k];
        }
        if (lane == 0) sthr[w] = T + 1e-3f + 4e-6f * fabsf(T);   // proxy f32-error margin
    }
    __syncthreads();

    float thr[QB];
    #pragma unroll
    for (int q = 0; q < QB; ++q) thr[q] = sthr[q];

    // ---- pass 2: re-stream, collect {pr <= thr[q]} (self collected too) ----
    #pragma unroll 2
    for (int s = 0; s < 16; ++s) {
        const int j = (s << 9) + tid;
        const float4 pj = pos4[j];
        #pragma unroll
        for (int q = 0; q < QB; ++q) {
            const float dot = fmaf(qx[q], pj.x, fmaf(qy[q], pj.y, qz[q] * pj.z));
            const float pr  = fmaf(-2.0f, dot, pj.w);
            if (pr <= thr[q]) {
                const int slot = atomicAdd(&s_cnt[q], 1);
                if (slot < 96) s_buf[q][slot] = j;
            }
        }
    }
    __syncthreads();

    // ---- pass 3: wave w does exact (f64 dist, idx) rank for query w; self removed ----
    {
        const int q  = w;
        const int iq = i0 + q;
        const int cno = s_cnt[q];
        if (cno <= 96) {
            const int cn = cno;
            const double dqx = (double)qx[q], dqy = (double)qy[q], dqz = (double)qz[q];
            for (int sl = lane; sl < cn; sl += 64) {
                const int jj = s_buf[q][sl];
                const float4 pj = pos4[jj];
                const double dx = dqx - (double)pj.x;
                const double dy = dqy - (double)pj.y;
                const double dz = dqz - (double)pj.z;
                s_d[q][sl] = dx*dx + dy*dy + dz*dz;
            }
            for (int sl = lane; sl < cn; sl += 64) {
                const int jj = s_buf[q][sl];
                if (jj == iq) continue;
                const double dj = s_d[q][sl];
                int r = 0;
                for (int e = 0; e < cn; ++e) {
                    const double de = s_d[q][e];
                    const int    je = s_buf[q][e];
                    r += (de < dj || (de == dj && je < jj)) ? 1 : 0;
                }
                const int selfb = (dj > 0.0 || (dj == 0.0 && iq < jj)) ? 1 : 0;
                const int rr = r - selfb;
                if (rr < K) idx_out[iq*K + rr] = jj;
            }
        } else {
            if (lane == 0) {
                for (int kk = 0; kk < K; ++kk) { s_fd[w][kk] = 1e300; s_fi[w][kk] = 0x7fffffff; }
                const double dqx = (double)qx[q], dqy = (double)qy[q], dqz = (double)qz[q];
                for (int j = 0; j < N; ++j) {
                    if (j == iq) continue;
                    const float4 pj = pos4[j];
                    const double dx = dqx - (double)pj.x;
                    const double dy = dqy - (double)pj.y;
                    const double dz = dqz - (double)pj.z;
                    const double dd = dx*dx + dy*dy + dz*dz;
                    if (dd < s_fd[w][K-1] || (dd == s_fd[w][K-1] && j < s_fi[w][K-1])) {
                        int p = K - 1;
                        while (p > 0 && (dd < s_fd[w][p-1] || (dd == s_fd[w][p-1] && j < s_fi[w][p-1]))) {
                            s_fd[w][p] = s_fd[w][p-1]; s_fi[w][p] = s_fi[w][p-1]; --p;
                        }
                        s_fd[w][p] = dd; s_fi[w][p] = j;
                    }
                }
                for (int kk = 0; kk < K; ++kk) idx_out[iq*K + kk] = s_fi[w][kk];
            }
        }
    }
}

// ---------------- Kernel 2: projections, weights in registers, 8 nodes/block ----------------
__global__ __launch_bounds__(192) void lin3_kernel(const float* __restrict__ x,
    const float* __restrict__ w_src, const float* __restrict__ w_dst,
    const float* __restrict__ w_lin, const float* __restrict__ b_lin,
    float* __restrict__ a_dst, float* __restrict__ a_src, float* __restrict__ v) {
    __shared__ float xr[LNODES][C];
    const int n0  = blockIdx.x * LNODES;
    const int tid = threadIdx.x;
    const int cc  = tid & 63;
    const int m   = tid >> 6;

    const float* w = (m == 0) ? w_dst : (m == 1) ? w_src : w_lin;
    float wreg[C];
    #pragma unroll
    for (int k = 0; k < C; ++k) wreg[k] = w[k*C + cc];

    for (int t = tid; t < LNODES*C; t += 192) xr[t >> 6][t & 63] = x[n0*C + t];
    __syncthreads();

    const float binit = (m == 2) ? b_lin[cc] : 0.0f;
    float* o = (m == 0) ? a_dst : (m == 1) ? a_src : v;
    for (int nn = 0; nn < LNODES; ++nn) {
        float acc = binit;
        const float4* xv = (const float4*)xr[nn];
        #pragma unroll
        for (int k4 = 0; k4 < 16; ++k4) {
            const float4 xx = xv[k4];
            acc = fmaf(xx.x, wreg[4*k4+0], acc);
            acc = fmaf(xx.y, wreg[4*k4+1], acc);
            acc = fmaf(xx.z, wreg[4*k4+2], acc);
            acc = fmaf(xx.w, wreg[4*k4+3], acc);
        }
        o[(n0 + nn)*C + cc] = acc;
    }
}

// ---- 16x64 @ 64x64 via 8 MFMA (A: wave-private bf16 tile, B: transposed bf16 weights) ----
__device__ __forceinline__ void mm16x64(const unsigned short* Hb, const unsigned short* wT,
                                        int c0, int sg, f32x4v acc[4]) {
    const bf16x8 a0 = *reinterpret_cast<const bf16x8*>(Hb + c0*HS + sg*8);
    const bf16x8 a1 = *reinterpret_cast<const bf16x8*>(Hb + c0*HS + 32 + sg*8);
    #pragma unroll
    for (int q = 0; q < 4; ++q) {
        const unsigned short* wr = wT + (q*16 + c0)*HS + sg*8;
        const bf16x8 b0 = *reinterpret_cast<const bf16x8*>(wr);
        const bf16x8 b1 = *reinterpret_cast<const bf16x8*>(wr + 32);
        acc[q] = __builtin_amdgcn_mfma_f32_16x16x32_bf16(a0, b0, acc[q], 0, 0, 0);
        acc[q] = __builtin_amdgcn_mfma_f32_16x16x32_bf16(a1, b1, acc[q], 0, 0, 0);
    }
}

// ---------------- Kernel 3: edge pipeline, wave-per-node, MFMA; staging = float4 copy ------
__global__ __launch_bounds__(512, 4) void edge_kernel(
    const float* __restrict__ x, const float* __restrict__ pos,
    const int* __restrict__ nidx,
    const float* __restrict__ a_dst, const float* __restrict__ a_src, const float* __restrict__ v,
    const unsigned short* __restrict__ wTg,
    const float* __restrict__ p1w, const float* __restrict__ p1b,
    const float* __restrict__ p1g, const float* __restrict__ p1bt,
    const float* __restrict__ p2b,
    const float* __restrict__ a1b, const float* __restrict__ a1g, const float* __restrict__ a1bt,
    const float* __restrict__ a2b,
    const float* __restrict__ uw, const float* __restrict__ ub,
    float* __restrict__ out) {

    __shared__ __align__(16) unsigned short sWT[3 * C * HS];
    __shared__ __align__(16) float          uwf[C * C];
    __shared__ __align__(16) unsigned short sHb[NB * K * HS];
    __shared__ __align__(16) float4         sMisc4[NB * 16];
    __shared__ int                          sIdx[NB * K];

    const int tid  = threadIdx.x;
    const int w    = tid >> 6;
    const int lane = tid & 63;
    const int c0   = tid & 15;
    const int sg   = (tid >> 4) & 3;
    const int n    = blockIdx.x * NB + w;

    unsigned short* Hlb = sHb + w * (K * HS);
    float4*         Ml4 = sMisc4 + w * 16;
    float*          Mlf = (float*)Ml4;
    int*            Il  = sIdx + w * K;

    // ---- staging: pre-transposed bf16 weights (float4 copy) + f32 uw ----
    {
        const float4* s4 = (const float4*)wTg;          // 1728 float4
        float4* d4 = (float4*)sWT;
        #pragma unroll
        for (int q = 0; q < 4; ++q) {
            const int e = tid + q*512;
            if (e < 1728) d4[e] = s4[e];
        }
        float4* du = (float4*)uwf;
        const float4* su = (const float4*)uw;
        du[tid] = su[tid]; du[tid + 512] = su[tid + 512];
    }
    if (lane < K) {
        const int j = nidx[n*K + lane];
        Il[lane] = j;
        float4 r;
        r.x = pos[3*n]   - pos[3*j];
        r.y = pos[3*n+1] - pos[3*j+1];
        r.z = pos[3*n+2] - pos[3*j+2];
        r.w = 0.0f;
        Ml4[lane] = r;
    }
    __syncthreads();   // the ONLY block barrier

    int c4[4];
    #pragma unroll
    for (int q = 0; q < 4; ++q) c4[q] = q*16 + c0;

    {
        float W0[4], W1[4], W2[4], B_[4], G_[4], BT[4];
        #pragma unroll
        for (int q = 0; q < 4; ++q) {
            const int cc = c4[q];
            W0[q] = p1w[cc]; W1[q] = p1w[C + cc]; W2[q] = p1w[2*C + cc];
            B_[q] = p1b[cc]; G_[q] = p1g[cc];     BT[q] = p1bt[cc];
        }
        #pragma unroll
        for (int r = 0; r < 4; ++r) {
            const float4 rr = Ml4[sg*4 + r];
            #pragma unroll
            for (int q = 0; q < 4; ++q) {
                float t = fmaf(rr.x, W0[q], fmaf(rr.y, W1[q], fmaf(rr.z, W2[q], B_[q])));
                t = fmaxf(fmaf(G_[q], t, BT[q]), 0.0f);
                Hlb[(sg*4 + r)*HS + c4[q]] = bfr(t);
            }
        }
    }

    f32x4v acc[4], del[4];
    #pragma unroll
    for (int q = 0; q < 4; ++q) { const float b_ = p2b[c4[q]]; acc[q] = (f32x4v){b_, b_, b_, b_}; }
    mm16x64(Hlb, sWT, c0, sg, acc);
    #pragma unroll
    for (int q = 0; q < 4; ++q) del[q] = acc[q];

    int jr[4];
    #pragma unroll
    for (int r = 0; r < 4; ++r) jr[r] = Il[sg*4 + r];
    float adstv[4];
    #pragma unroll
    for (int q = 0; q < 4; ++q) adstv[q] = a_dst[n*C + c4[q]];

    #pragma unroll
    for (int r = 0; r < 4; ++r) {
        #pragma unroll
        for (int q = 0; q < 4; ++q) {
            const float t = adstv[q] - a_src[jr[r]*C + c4[q]] + acc[q][r];
            Hlb[(sg*4 + r)*HS + c4[q]] = bfr(t);
        }
    }

    #pragma unroll
    for (int q = 0; q < 4; ++q) { const float b_ = a1b[c4[q]]; acc[q] = (f32x4v){b_, b_, b_, b_}; }
    mm16x64(Hlb, sWT + C*HS, c0, sg, acc);
    #pragma unroll
    for (int q = 0; q < 4; ++q) {
        const float g_ = a1g[c4[q]], bt_ = a1bt[c4[q]];
        #pragma unroll
        for (int r = 0; r < 4; ++r) {
            const float h2 = fmaxf(fmaf(g_, acc[q][r], bt_), 0.0f);
            Hlb[(sg*4 + r)*HS + c4[q]] = bfr(h2);
        }
    }

    #pragma unroll
    for (int q = 0; q < 4; ++q) { const float b_ = a2b[c4[q]]; acc[q] = (f32x4v){b_, b_, b_, b_}; }
    mm16x64(Hlb, sWT + 2*C*HS, c0, sg, acc);

    float o_[4];
    #pragma unroll
    for (int q = 0; q < 4; ++q) {
        float vgq[4];
        #pragma unroll
        for (int r = 0; r < 4; ++r) vgq[r] = v[jr[r]*C + c4[q]];
        float lm = fmaxf(fmaxf(acc[q][0], acc[q][1]), fmaxf(acc[q][2], acc[q][3]));
        lm = fmaxf(lm, __shfl_xor(lm, 16, 64));
        lm = fmaxf(lm, __shfl_xor(lm, 32, 64));
        float ls = 0.0f, lo = 0.0f;
        #pragma unroll
        for (int r = 0; r < 4; ++r) {
            const float e_ = __expf(acc[q][r] - lm);
            ls += e_;
            lo = fmaf(e_, vgq[r] + del[q][r], lo);
        }
        ls += __shfl_xor(ls, 16, 64); ls += __shfl_xor(ls, 32, 64);
        lo += __shfl_xor(lo, 16, 64); lo += __shfl_xor(lo, 32, 64);
        o_[q] = lo / ls;
    }
    if (sg == 0) {
        #pragma unroll
        for (int q = 0; q < 4; ++q) Mlf[c4[q]] = o_[q];
    }

    float facc = ub[lane] + x[n*C + lane];
    #pragma unroll 4
    for (int e4 = 0; e4 < 16; ++e4) {
        const float4 g4 = Ml4[e4];
        facc = fmaf(g4.x, uwf[(e4*4+0)*C + lane], facc);
        facc = fmaf(g4.y, uwf[(e4*4+1)*C + lane], facc);
        facc = fmaf(g4.z, uwf[(e4*4+2)*C + lane], facc);
        facc = fmaf(g4.w, uwf[(e4*4+3)*C + lane], facc);
    }
    out[n*C + lane] = facc;
}

extern "C" void kernel_launch(void* const* d_in, const int* in_sizes, int n_in,
                              void* d_out, int out_size, void* d_ws, size_t ws_size,
                              hipStream_t stream) {
    const float* x     = (const float*)d_in[0];
    const float* pos   = (const float*)d_in[1];
    const float* w_src = (const float*)d_in[2];
    const float* w_dst = (const float*)d_in[3];
    const float* w_lin = (const float*)d_in[4];
    const float* b_lin = (const float*)d_in[5];
    const float* p1w   = (const float*)d_in[6];
    const float* p1b   = (const float*)d_in[7];
    const float* p1g   = (const float*)d_in[8];
    const float* p1bt  = (const float*)d_in[9];
    const float* p2w   = (const float*)d_in[10];
    const float* p2b   = (const float*)d_in[11];
    const float* a1w   = (const float*)d_in[12];
    const float* a1b   = (const float*)d_in[13];
    const float* a1g   = (const float*)d_in[14];
    const float* a1bt  = (const float*)d_in[15];
    const float* a2w   = (const float*)d_in[16];
    const float* a2b   = (const float*)d_in[17];
    const float* uw    = (const float*)d_in[18];
    const float* ub    = (const float*)d_in[19];
    float* out = (float*)d_out;

    char* ws    = (char*)d_ws;
    int*    idx  = (int*)ws;                                    // N*K ints
    float*  adst = (float*)(ws + (size_t)N*K*sizeof(int));
    float*  asrc = adst + (size_t)N*C;
    float*  vv   = asrc + (size_t)N*C;
    float4* pos4 = (float4*)(vv + (size_t)N*C);                 // N float4
    unsigned short* wTg = (unsigned short*)(pos4 + N);          // 3*C*HS bf16

    prep_pos4 <<<(N + 255)/256, 256, 0, stream>>>(pos, pos4);
    prep_wT   <<<(3*C*C + 255)/256, 256, 0, stream>>>(p2w, a1w, a2w, wTg);
    knn_kernel<<<N/QB, 512, 0, stream>>>(pos4, idx);
    lin3_kernel<<<N/LNODES, 192, 0, stream>>>(x, w_src, w_dst, w_lin, b_lin, adst, asrc, vv);
    edge_kernel<<<N/NB, 512, 0, stream>>>(x, pos, idx, adst, asrc, vv, wTg,
        p1w, p1b, p1g, p1bt, p2b, a1b, a1g, a1bt, a2b, uw, ub, out);
}

// Round 10
// 62.877 us; speedup vs baseline: 1.9543x; 1.2850x over previous
//
#include <hip/hip_runtime.h>
#include <math.h>

#define N 8192
#define C 64
#define K 16
#define NB 8
#define QB 8
#define LNODES 8
#define HS 72   // bf16 row stride (elements) for LDS tiles: 144B, 16B-aligned, bank-uniform

typedef unsigned long long u64;
typedef unsigned int u32;

typedef float  f32x4v  __attribute__((ext_vector_type(4)));
typedef __bf16 bf16x8  __attribute__((ext_vector_type(8)));

__device__ __forceinline__ unsigned short bfr(float f) {   // f32 -> bf16 RTNE
    u32 u = __float_as_uint(f);
    return (unsigned short)((u + 0x7fffu + ((u >> 16) & 1u)) >> 16);
}

// ---------------- prep: pack pos into float4, w = |p|^2 ----------------
__global__ __launch_bounds__(256) void prep_pos4(const float* __restrict__ pos,
                                                 float4* __restrict__ pos4) {
    int j = blockIdx.x * 256 + threadIdx.x;
    if (j < N) {
        const float px = pos[3*j], py = pos[3*j+1], pz = pos[3*j+2];
        pos4[j] = make_float4(px, py, pz, fmaf(px, px, fmaf(py, py, pz * pz)));
    }
}

// ---------------- prep: bf16-transposed edge weights wT[m][c][e] ----------------
__global__ __launch_bounds__(256) void prep_wT(const float* __restrict__ p2w,
                                               const float* __restrict__ a1w,
                                               const float* __restrict__ a2w,
                                               unsigned short* __restrict__ wT) {
    int t = blockIdx.x * 256 + threadIdx.x;
    if (t < 3 * C * C) {
        const int m = t >> 12, r = t & (C*C - 1);
        const int e = r >> 6, c = r & 63;
        const float* w = (m == 0) ? p2w : (m == 1) ? a1w : a2w;
        wT[m * C * HS + c * HS + e] = bfr(w[r]);
    }
}

// ---------------- Kernel 1: KNN, block-per-8-queries, sparse rescan ----------------
// Pass 1: thread t streams 16 disjoint candidates (j = s*512+t), proxy pr = |pj|^2-2*dot
// per query; minima -> LDS. Wave w (query w): T = 17th-smallest lane-min (17 popped lanes =
// 17 disjoint subsets => coverage); thr = T + margin. List threads with smin<=thr (~20);
// rescan ONLY their subsets (bit-identical proxy test) -> collected = {pr<=thr} exactly.
// Exact (f64,idx) rank over collected, self removed by index. Fallback: serial exact.
__global__ __launch_bounds__(512) void knn_kernel(const float4* __restrict__ pos4,
                                                  int* __restrict__ idx_out) {
    __shared__ float          smin[QB][512];   // 16 KB
    __shared__ float          sthr[QB];
    __shared__ unsigned short s_tl[QB][64];    // candidate-owning thread list (1 KB)
    __shared__ int            s_tlc[QB];
    __shared__ int            s_buf[QB][96];   // 3 KB
    __shared__ double         s_d[QB][96];     // 6 KB
    __shared__ int            s_cnt[QB];
    __shared__ double         s_fd[QB][K];     // fallback (pathological only)
    __shared__ int            s_fi[QB][K];

    const int tid  = threadIdx.x;
    const int w    = tid >> 6;
    const int lane = tid & 63;
    const int i0   = blockIdx.x * QB;

    if (tid < QB) { s_cnt[tid] = 0; s_tlc[tid] = 0; }

    float qx[QB], qy[QB], qz[QB];
    #pragma unroll
    for (int q = 0; q < QB; ++q) {
        const float4 p = pos4[i0 + q];
        qx[q] = p.x; qy[q] = p.y; qz[q] = p.z;
    }

    // ---- pass 1: per-thread proxy-min per query over 16 disjoint candidates ----
    float mn[QB];
    #pragma unroll
    for (int q = 0; q < QB; ++q) mn[q] = INFINITY;
    #pragma unroll 4
    for (int s = 0; s < 16; ++s) {
        const int j = (s << 9) + tid;
        const float4 pj = pos4[j];
        #pragma unroll
        for (int q = 0; q < QB; ++q) {
            const float dot = fmaf(qx[q], pj.x, fmaf(qy[q], pj.y, qz[q] * pj.z));
            const float pr  = fmaf(-2.0f, dot, pj.w);
            mn[q] = fminf(mn[q], pr);
        }
    }
    #pragma unroll
    for (int q = 0; q < QB; ++q) smin[q][tid] = mn[q];
    __syncthreads();   // the only block barrier; everything below is wave-private

    // ---- wave w: T = 17th-smallest lane-min; list threads with smin <= thr ----
    float thw;
    {
        float v[8];
        #pragma unroll
        for (int k = 0; k < 8; ++k) v[k] = smin[w][lane + 64*k];
        float ml = fminf(fminf(fminf(v[0], v[1]), fminf(v[2], v[3])),
                         fminf(fminf(v[4], v[5]), fminf(v[6], v[7])));
        float cur = ml, T = 0.0f;
        for (int r = 0; r < K + 1; ++r) {   // 17 rounds; dup-pops only enlarge T
            float m = cur;
            #pragma unroll
            for (int off = 32; off; off >>= 1) m = fminf(m, __shfl_xor(m, off, 64));
            T = m;
            cur = (cur == m) ? INFINITY : cur;
        }
        thw = T + 1e-3f + 4e-6f * fabsf(T);   // proxy f32-error margin (2*eps bound)
        if (lane == 0) sthr[w] = thw;
        #pragma unroll
        for (int k = 0; k < 8; ++k) {
            if (v[k] <= thw) {
                const int slot = atomicAdd(&s_tlc[w], 1);
                if (slot < 64) s_tl[w][slot] = (unsigned short)(lane + 64*k);
            }
        }
    }

    // ---- sparse rescan: only listed threads' subsets (bit-identical proxy test) ----
    {
        const int lc_raw = s_tlc[w];
        const int lc = lc_raw < 64 ? lc_raw : 64;
        const float qwx = qx[w], qwy = qy[w], qwz = qz[w];
        for (int p = lane; p < lc * 16; p += 64) {
            const int t = s_tl[w][p >> 4];
            const int s = p & 15;
            const int j = (s << 9) + t;
            const float4 pj = pos4[j];
            const float dot = fmaf(qwx, pj.x, fmaf(qwy, pj.y, qwz * pj.z));
            const float pr  = fmaf(-2.0f, dot, pj.w);
            if (pr <= thw) {
                const int slot = atomicAdd(&s_cnt[w], 1);
                if (slot < 96) s_buf[w][slot] = j;
            }
        }
    }

    // ---- exact (f64 dist, idx) rank for query w; self removed by index ----
    {
        const int q  = w;
        const int iq = i0 + q;
        const int cno = s_cnt[q];
        if (cno <= 96 && s_tlc[q] <= 64) {
            const int cn = cno;
            const double dqx = (double)qx[q], dqy = (double)qy[q], dqz = (double)qz[q];
            for (int sl = lane; sl < cn; sl += 64) {
                const int jj = s_buf[q][sl];
                const float4 pj = pos4[jj];
                const double dx = dqx - (double)pj.x;
                const double dy = dqy - (double)pj.y;
                const double dz = dqz - (double)pj.z;
                s_d[q][sl] = dx*dx + dy*dy + dz*dz;
            }
            for (int sl = lane; sl < cn; sl += 64) {
                const int jj = s_buf[q][sl];
                if (jj == iq) continue;
                const double dj = s_d[q][sl];
                int r = 0;
                for (int e = 0; e < cn; ++e) {
                    const double de = s_d[q][e];
                    const int    je = s_buf[q][e];
                    r += (de < dj || (de == dj && je < jj)) ? 1 : 0;
                }
                const int selfb = (dj > 0.0 || (dj == 0.0 && iq < jj)) ? 1 : 0;
                const int rr = r - selfb;
                if (rr < K) idx_out[iq*K + rr] = jj;
            }
        } else {
            if (lane == 0) {
                for (int kk = 0; kk < K; ++kk) { s_fd[w][kk] = 1e300; s_fi[w][kk] = 0x7fffffff; }
                const double dqx = (double)qx[q], dqy = (double)qy[q], dqz = (double)qz[q];
                for (int j = 0; j < N; ++j) {
                    if (j == iq) continue;
                    const float4 pj = pos4[j];
                    const double dx = dqx - (double)pj.x;
                    const double dy = dqy - (double)pj.y;
                    const double dz = dqz - (double)pj.z;
                    const double dd = dx*dx + dy*dy + dz*dz;
                    if (dd < s_fd[w][K-1] || (dd == s_fd[w][K-1] && j < s_fi[w][K-1])) {
                        int p = K - 1;
                        while (p > 0 && (dd < s_fd[w][p-1] || (dd == s_fd[w][p-1] && j < s_fi[w][p-1]))) {
                            s_fd[w][p] = s_fd[w][p-1]; s_fi[w][p] = s_fi[w][p-1]; --p;
                        }
                        s_fd[w][p] = dd; s_fi[w][p] = j;
                    }
                }
                for (int kk = 0; kk < K; ++kk) idx_out[iq*K + kk] = s_fi[w][kk];
            }
        }
    }
}

// ---------------- Kernel 2: projections, weights in registers, 8 nodes/block ----------------
__global__ __launch_bounds__(192) void lin3_kernel(const float* __restrict__ x,
    const float* __restrict__ w_src, const float* __restrict__ w_dst,
    const float* __restrict__ w_lin, const float* __restrict__ b_lin,
    float* __restrict__ a_dst, float* __restrict__ a_src, float* __restrict__ v) {
    __shared__ float xr[LNODES][C];
    const int n0  = blockIdx.x * LNODES;
    const int tid = threadIdx.x;
    const int cc  = tid & 63;
    const int m   = tid >> 6;

    const float* w = (m == 0) ? w_dst : (m == 1) ? w_src : w_lin;
    float wreg[C];
    #pragma unroll
    for (int k = 0; k < C; ++k) wreg[k] = w[k*C + cc];

    for (int t = tid; t < LNODES*C; t += 192) xr[t >> 6][t & 63] = x[n0*C + t];
    __syncthreads();

    const float binit = (m == 2) ? b_lin[cc] : 0.0f;
    float* o = (m == 0) ? a_dst : (m == 1) ? a_src : v;
    for (int nn = 0; nn < LNODES; ++nn) {
        float acc = binit;
        const float4* xv = (const float4*)xr[nn];
        #pragma unroll
        for (int k4 = 0; k4 < 16; ++k4) {
            const float4 xx = xv[k4];
            acc = fmaf(xx.x, wreg[4*k4+0], acc);
            acc = fmaf(xx.y, wreg[4*k4+1], acc);
            acc = fmaf(xx.z, wreg[4*k4+2], acc);
            acc = fmaf(xx.w, wreg[4*k4+3], acc);
        }
        o[(n0 + nn)*C + cc] = acc;
    }
}

// ---- 16x64 @ 64x64 via 8 MFMA (A: wave-private bf16 tile, B: transposed bf16 weights) ----
__device__ __forceinline__ void mm16x64(const unsigned short* Hb, const unsigned short* wT,
                                        int c0, int sg, f32x4v acc[4]) {
    const bf16x8 a0 = *reinterpret_cast<const bf16x8*>(Hb + c0*HS + sg*8);
    const bf16x8 a1 = *reinterpret_cast<const bf16x8*>(Hb + c0*HS + 32 + sg*8);
    #pragma unroll
    for (int q = 0; q < 4; ++q) {
        const unsigned short* wr = wT + (q*16 + c0)*HS + sg*8;
        const bf16x8 b0 = *reinterpret_cast<const bf16x8*>(wr);
        const bf16x8 b1 = *reinterpret_cast<const bf16x8*>(wr + 32);
        acc[q] = __builtin_amdgcn_mfma_f32_16x16x32_bf16(a0, b0, acc[q], 0, 0, 0);
        acc[q] = __builtin_amdgcn_mfma_f32_16x16x32_bf16(a1, b1, acc[q], 0, 0, 0);
    }
}

// ---------------- Kernel 3: edge pipeline, wave-per-node, MFMA (unchanged) ----------------
__global__ __launch_bounds__(512, 4) void edge_kernel(
    const float* __restrict__ x, const float* __restrict__ pos,
    const int* __restrict__ nidx,
    const float* __restrict__ a_dst, const float* __restrict__ a_src, const float* __restrict__ v,
    const unsigned short* __restrict__ wTg,
    const float* __restrict__ p1w, const float* __restrict__ p1b,
    const float* __restrict__ p1g, const float* __restrict__ p1bt,
    const float* __restrict__ p2b,
    const float* __restrict__ a1b, const float* __restrict__ a1g, const float* __restrict__ a1bt,
    const float* __restrict__ a2b,
    const float* __restrict__ uw, const float* __restrict__ ub,
    float* __restrict__ out) {

    __shared__ __align__(16) unsigned short sWT[3 * C * HS];
    __shared__ __align__(16) float          uwf[C * C];
    __shared__ __align__(16) unsigned short sHb[NB * K * HS];
    __shared__ __align__(16) float4         sMisc4[NB * 16];
    __shared__ int                          sIdx[NB * K];

    const int tid  = threadIdx.x;
    const int w    = tid >> 6;
    const int lane = tid & 63;
    const int c0   = tid & 15;
    const int sg   = (tid >> 4) & 3;
    const int n    = blockIdx.x * NB + w;

    unsigned short* Hlb = sHb + w * (K * HS);
    float4*         Ml4 = sMisc4 + w * 16;
    float*          Mlf = (float*)Ml4;
    int*            Il  = sIdx + w * K;

    {
        const float4* s4 = (const float4*)wTg;          // 1728 float4
        float4* d4 = (float4*)sWT;
        #pragma unroll
        for (int q = 0; q < 4; ++q) {
            const int e = tid + q*512;
            if (e < 1728) d4[e] = s4[e];
        }
        float4* du = (float4*)uwf;
        const float4* su = (const float4*)uw;
        du[tid] = su[tid]; du[tid + 512] = su[tid + 512];
    }
    if (lane < K) {
        const int j = nidx[n*K + lane];
        Il[lane] = j;
        float4 r;
        r.x = pos[3*n]   - pos[3*j];
        r.y = pos[3*n+1] - pos[3*j+1];
        r.z = pos[3*n+2] - pos[3*j+2];
        r.w = 0.0f;
        Ml4[lane] = r;
    }
    __syncthreads();   // the ONLY block barrier

    int c4[4];
    #pragma unroll
    for (int q = 0; q < 4; ++q) c4[q] = q*16 + c0;

    {
        float W0[4], W1[4], W2[4], B_[4], G_[4], BT[4];
        #pragma unroll
        for (int q = 0; q < 4; ++q) {
            const int cc = c4[q];
            W0[q] = p1w[cc]; W1[q] = p1w[C + cc]; W2[q] = p1w[2*C + cc];
            B_[q] = p1b[cc]; G_[q] = p1g[cc];     BT[q] = p1bt[cc];
        }
        #pragma unroll
        for (int r = 0; r < 4; ++r) {
            const float4 rr = Ml4[sg*4 + r];
            #pragma unroll
            for (int q = 0; q < 4; ++q) {
                float t = fmaf(rr.x, W0[q], fmaf(rr.y, W1[q], fmaf(rr.z, W2[q], B_[q])));
                t = fmaxf(fmaf(G_[q], t, BT[q]), 0.0f);
                Hlb[(sg*4 + r)*HS + c4[q]] = bfr(t);
            }
        }
    }

    f32x4v acc[4], del[4];
    #pragma unroll
    for (int q = 0; q < 4; ++q) { const float b_ = p2b[c4[q]]; acc[q] = (f32x4v){b_, b_, b_, b_}; }
    mm16x64(Hlb, sWT, c0, sg, acc);
    #pragma unroll
    for (int q = 0; q < 4; ++q) del[q] = acc[q];

    int jr[4];
    #pragma unroll
    for (int r = 0; r < 4; ++r) jr[r] = Il[sg*4 + r];
    float adstv[4];
    #pragma unroll
    for (int q = 0; q < 4; ++q) adstv[q] = a_dst[n*C + c4[q]];

    #pragma unroll
    for (int r = 0; r < 4; ++r) {
        #pragma unroll
        for (int q = 0; q < 4; ++q) {
            const float t = adstv[q] - a_src[jr[r]*C + c4[q]] + acc[q][r];
            Hlb[(sg*4 + r)*HS + c4[q]] = bfr(t);
        }
    }

    #pragma unroll
    for (int q = 0; q < 4; ++q) { const float b_ = a1b[c4[q]]; acc[q] = (f32x4v){b_, b_, b_, b_}; }
    mm16x64(Hlb, sWT + C*HS, c0, sg, acc);
    #pragma unroll
    for (int q = 0; q < 4; ++q) {
        const float g_ = a1g[c4[q]], bt_ = a1bt[c4[q]];
        #pragma unroll
        for (int r = 0; r < 4; ++r) {
            const float h2 = fmaxf(fmaf(g_, acc[q][r], bt_), 0.0f);
            Hlb[(sg*4 + r)*HS + c4[q]] = bfr(h2);
        }
    }

    #pragma unroll
    for (int q = 0; q < 4; ++q) { const float b_ = a2b[c4[q]]; acc[q] = (f32x4v){b_, b_, b_, b_}; }
    mm16x64(Hlb, sWT + 2*C*HS, c0, sg, acc);

    float o_[4];
    #pragma unroll
    for (int q = 0; q < 4; ++q) {
        float vgq[4];
        #pragma unroll
        for (int r = 0; r < 4; ++r) vgq[r] = v[jr[r]*C + c4[q]];
        float lm = fmaxf(fmaxf(acc[q][0], acc[q][1]), fmaxf(acc[q][2], acc[q][3]));
        lm = fmaxf(lm, __shfl_xor(lm, 16, 64));
        lm = fmaxf(lm, __shfl_xor(lm, 32, 64));
        float ls = 0.0f, lo = 0.0f;
        #pragma unroll
        for (int r = 0; r < 4; ++r) {
            const float e_ = __expf(acc[q][r] - lm);
            ls += e_;
            lo = fmaf(e_, vgq[r] + del[q][r], lo);
        }
        ls += __shfl_xor(ls, 16, 64); ls += __shfl_xor(ls, 32, 64);
        lo += __shfl_xor(lo, 16, 64); lo += __shfl_xor(lo, 32, 64);
        o_[q] = lo / ls;
    }
    if (sg == 0) {
        #pragma unroll
        for (int q = 0; q < 4; ++q) Mlf[c4[q]] = o_[q];
    }

    float facc = ub[lane] + x[n*C + lane];
    #pragma unroll 4
    for (int e4 = 0; e4 < 16; ++e4) {
        const float4 g4 = Ml4[e4];
        facc = fmaf(g4.x, uwf[(e4*4+0)*C + lane], facc);
        facc = fmaf(g4.y, uwf[(e4*4+1)*C + lane], facc);
        facc = fmaf(g4.z, uwf[(e4*4+2)*C + lane], facc);
        facc = fmaf(g4.w, uwf[(e4*4+3)*C + lane], facc);
    }
    out[n*C + lane] = facc;
}

extern "C" void kernel_launch(void* const* d_in, const int* in_sizes, int n_in,
                              void* d_out, int out_size, void* d_ws, size_t ws_size,
                              hipStream_t stream) {
    const float* x     = (const float*)d_in[0];
    const float* pos   = (const float*)d_in[1];
    const float* w_src = (const float*)d_in[2];
    const float* w_dst = (const float*)d_in[3];
    const float* w_lin = (const float*)d_in[4];
    const float* b_lin = (const float*)d_in[5];
    const float* p1w   = (const float*)d_in[6];
    const float* p1b   = (const float*)d_in[7];
    const float* p1g   = (const float*)d_in[8];
    const float* p1bt  = (const float*)d_in[9];
    const float* p2w   = (const float*)d_in[10];
    const float* p2b   = (const float*)d_in[11];
    const float* a1w   = (const float*)d_in[12];
    const float* a1b   = (const float*)d_in[13];
    const float* a1g   = (const float*)d_in[14];
    const float* a1bt  = (const float*)d_in[15];
    const float* a2w   = (const float*)d_in[16];
    const float* a2b   = (const float*)d_in[17];
    const float* uw    = (const float*)d_in[18];
    const float* ub    = (const float*)d_in[19];
    float* out = (float*)d_out;

    char* ws    = (char*)d_ws;
    int*    idx  = (int*)ws;                                    // N*K ints
    float*  adst = (float*)(ws + (size_t)N*K*sizeof(int));
    float*  asrc = adst + (size_t)N*C;
    float*  vv   = asrc + (size_t)N*C;
    float4* pos4 = (float4*)(vv + (size_t)N*C);                 // N float4
    unsigned short* wTg = (unsigned short*)(pos4 + N);          // 3*C*HS bf16

    prep_pos4 <<<(N + 255)/256, 256, 0, stream>>>(pos, pos4);
    prep_wT   <<<(3*C*C + 255)/256, 256, 0, stream>>>(p2w, a1w, a2w, wTg);
    knn_kernel<<<N/QB, 512, 0, stream>>>(pos4, idx);
    lin3_kernel<<<N/LNODES, 192, 0, stream>>>(x, w_src, w_dst, w_lin, b_lin, adst, asrc, vv);
    edge_kernel<<<N/NB, 512, 0, stream>>>(x, pos, idx, adst, asrc, vv, wTg,
        p1w, p1b, p1g, p1bt, p2b, a1b, a1g, a1bt, a2b, uw, ub, out);
}